// Round 9
// baseline (258.499 us; speedup 1.0000x reference)
//
#include <hip/hip_runtime.h>
#include <hip/hip_bf16.h>
#include <stdint.h>

typedef __hip_bfloat16 bf16;
typedef __attribute__((ext_vector_type(8))) __bf16 frag8;
typedef __attribute__((ext_vector_type(4))) float f32x4;

// ---------------- helpers ----------------
__device__ inline float wred_sum(float v) {
#pragma unroll
  for (int o = 32; o; o >>= 1) v += __shfl_down(v, o);
  return v;
}
__device__ inline float wred_max(float v) {
#pragma unroll
  for (int o = 32; o; o >>= 1) v = fmaxf(v, __shfl_down(v, o));
  return v;
}
__device__ inline unsigned short bits_of(bf16 h) { return *(unsigned short*)&h; }
__device__ inline frag8 cvt8(float4 lo, float4 hi) {
  union { frag8 f; unsigned short u[8]; } r;
  r.u[0] = bits_of(__float2bfloat16(lo.x));
  r.u[1] = bits_of(__float2bfloat16(lo.y));
  r.u[2] = bits_of(__float2bfloat16(lo.z));
  r.u[3] = bits_of(__float2bfloat16(lo.w));
  r.u[4] = bits_of(__float2bfloat16(hi.x));
  r.u[5] = bits_of(__float2bfloat16(hi.y));
  r.u[6] = bits_of(__float2bfloat16(hi.z));
  r.u[7] = bits_of(__float2bfloat16(hi.w));
  return r.f;
}

// ---------------- 1. W[256][768] f32 -> Wt[768][256] bf16 ----------------------
__global__ __launch_bounds__(256) void wt_k(const float* __restrict__ W,
                                            bf16* __restrict__ Wt) {
  __shared__ float t[32][33];
  int c0 = blockIdx.x * 32, o0 = blockIdx.y * 32;
  int tx = threadIdx.x & 31, ty = threadIdx.x >> 5;
#pragma unroll
  for (int i = 0; i < 4; ++i)
    t[ty + i * 8][tx] = W[(long)(o0 + ty + i * 8) * 768 + c0 + tx];
  __syncthreads();
#pragma unroll
  for (int i = 0; i < 4; ++i)
    Wt[(long)(c0 + ty + i * 8) * 256 + o0 + tx] = __float2bfloat16(t[tx][ty + i * 8]);
}

// ---------------- 2. small barrier-free GEMM, one wave per 64x64 tile ----------
// C[m][n] = sum_k A[m][k]*B[n][k] (+ bias[n]); A,B row-major with row stride K.
template <bool AF32, bool BF32, bool RELU, bool OUT_BF16, bool BIAS>
__global__ __launch_bounds__(64) void gemm_sm2(const void* __restrict__ Av,
                                               const void* __restrict__ Bv,
                                               void* __restrict__ C, int K, int ldc,
                                               const float* __restrict__ bias) {
  int n0 = blockIdx.x * 64, m0 = blockIdx.y * 64;
  int lr = threadIdx.x & 15, kg = threadIdx.x >> 4;
  f32x4 acc[4][4] = {};
#pragma unroll 2
  for (int k0 = 0; k0 < K; k0 += 32) {
    frag8 af[4], bv[4];
#pragma unroll
    for (int mi = 0; mi < 4; ++mi) {
      long row = m0 + mi * 16 + lr;
      if constexpr (AF32) {
        const float* ap = (const float*)Av + row * K + k0 + kg * 8;
        af[mi] = cvt8(*(const float4*)ap, *(const float4*)(ap + 4));
      } else {
        af[mi] = *(const frag8*)((const bf16*)Av + row * K + k0 + kg * 8);
      }
    }
#pragma unroll
    for (int ni = 0; ni < 4; ++ni) {
      long row = n0 + ni * 16 + lr;
      if constexpr (BF32) {
        const float* bp = (const float*)Bv + row * K + k0 + kg * 8;
        bv[ni] = cvt8(*(const float4*)bp, *(const float4*)(bp + 4));
      } else {
        bv[ni] = *(const frag8*)((const bf16*)Bv + row * K + k0 + kg * 8);
      }
    }
#pragma unroll
    for (int mi = 0; mi < 4; ++mi)
#pragma unroll
      for (int ni = 0; ni < 4; ++ni)
        acc[mi][ni] = __builtin_amdgcn_mfma_f32_16x16x32_bf16(af[mi], bv[ni],
                                                              acc[mi][ni], 0, 0, 0);
  }
#pragma unroll
  for (int mi = 0; mi < 4; ++mi)
#pragma unroll
    for (int ni = 0; ni < 4; ++ni)
#pragma unroll
      for (int j = 0; j < 4; ++j) {
        int row = m0 + mi * 16 + kg * 4 + j;
        int col = n0 + ni * 16 + lr;
        float v = acc[mi][ni][j];
        if (BIAS) v += bias[col];
        if (RELU) v = fmaxf(v, 0.f);
        long idx = (long)row * ldc + col;
        if constexpr (OUT_BF16) ((bf16*)C)[idx] = __float2bfloat16(v);
        else ((float*)C)[idx] = v;
      }
}

// ---------------- 3. logits2: lgt[cs][b*12+n][p] = sum_{c in half} embW*X ------
// Bias term emb.conv_b is constant over p -> drops out of softmax (shift-inv).
__global__ __launch_bounds__(256) void logits2(const float* __restrict__ X,
                                               const float* __restrict__ embW,
                                               float* __restrict__ lgt) {
  int px = blockIdx.x, cs = blockIdx.y, b = blockIdx.z;
  __shared__ float e[12 * 384];   // 18 KB
  for (int i = threadIdx.x; i < 12 * 384; i += 256)
    e[i] = embW[((long)b * 12 + i / 384) * 768 + cs * 384 + (i % 384)];
  __syncthreads();
  int p = px * 256 + threadIdx.x;
  if (p >= 1204) return;
  const float* xb = X + ((long)b * 768 + cs * 384) * 1204 + p;
  float acc[12] = {};
#pragma unroll 8
  for (int c = 0; c < 384; ++c) {
    float xv = xb[(long)c * 1204];
#pragma unroll
    for (int n = 0; n < 12; ++n) acc[n] += e[n * 384 + c] * xv;
  }
#pragma unroll
  for (int n = 0; n < 12; ++n)
    lgt[((long)cs * 384 + b * 12 + n) * 1204 + p] = acc[n];
}

// ---------------- 4. softmax (2 partials) -> am [32][16][1280] bf16 zero-pad ---
__global__ __launch_bounds__(256) void softmax2(const float* __restrict__ lgt,
                                                bf16* __restrict__ am) {
  int b = blockIdx.x, n = blockIdx.y, tid = threadIdx.x;
  bf16* row = am + ((long)b * 16 + n) * 1280;
  if (n >= 12) {
    for (int i = tid; i < 1280; i += 256) row[i] = __float2bfloat16(0.f);
    return;
  }
  const float* l0 = lgt + ((long)b * 12 + n) * 1204;
  const float* l1 = l0 + (long)384 * 1204;
  float vals[5];
  float m = -3.0e38f;
#pragma unroll
  for (int i = 0; i < 5; ++i) {
    int pp = tid + i * 256;
    vals[i] = (pp < 1204) ? (l0[pp] + l1[pp]) : -3.0e38f;
    m = fmaxf(m, vals[i]);
  }
  m = wred_max(m);
  __shared__ float rd[4];
  int w = tid >> 6, lane = tid & 63;
  if (lane == 0) rd[w] = m;
  __syncthreads();
  m = fmaxf(fmaxf(rd[0], rd[1]), fmaxf(rd[2], rd[3]));
  float s = 0.f;
#pragma unroll
  for (int i = 0; i < 5; ++i) {
    int pp = tid + i * 256;
    vals[i] = (pp < 1204) ? __expf(vals[i] - m) : 0.f;
    s += vals[i];
  }
  s = wred_sum(s);
  __syncthreads();
  if (lane == 0) rd[w] = s;
  __syncthreads();
  s = rd[0] + rd[1] + rd[2] + rd[3];
  float inv = 1.f / s;
#pragma unroll
  for (int i = 0; i < 5; ++i) {
    int pp = tid + i * 256;
    row[pp] = __float2bfloat16((pp < 1204) ? vals[i] * inv : 0.f);
  }
}

// ---------------- 5. ctx_a: Yp[kc][b][n][c] = sum_{p in chunk} X[b][c][p]A[n][p]
// TN MFMA with K = p: BOTH operands p-contiguous, no transpose. 1 wave/block.
__global__ __launch_bounds__(64) void ctx_a(const float* __restrict__ X,
                                            const bf16* __restrict__ am,
                                            float* __restrict__ Yp) {
  int ct = blockIdx.x, kc = blockIdx.y, b = blockIdx.z;
  int c0 = ct * 64;
  int kst = kc * 256, kend = min(kst + 256, 1204);
  int lr = threadIdx.x & 15, kg = threadIdx.x >> 4;
  f32x4 acc[4] = {};
  for (int k0 = kst; k0 < kend; k0 += 32) {
    frag8 bv = *(const frag8*)(am + ((long)b * 16 + lr) * 1280 + k0 + kg * 8);
    bool full = (k0 + 32 <= 1204);
#pragma unroll
    for (int mi = 0; mi < 4; ++mi) {
      const float* ap = X + ((long)b * 768 + c0 + mi * 16 + lr) * 1204 + k0 + kg * 8;
      frag8 av;
      if (full) {
        av = cvt8(*(const float4*)ap, *(const float4*)(ap + 4));
      } else {
        float t[8];
#pragma unroll
        for (int j = 0; j < 8; ++j)
          t[j] = (k0 + kg * 8 + j < 1204) ? ap[j] : 0.f;   // A=0 there anyway
        av = cvt8(make_float4(t[0], t[1], t[2], t[3]),
                  make_float4(t[4], t[5], t[6], t[7]));
      }
      acc[mi] = __builtin_amdgcn_mfma_f32_16x16x32_bf16(av, bv, acc[mi], 0, 0, 0);
    }
  }
  if (lr < 12) {
#pragma unroll
    for (int mi = 0; mi < 4; ++mi) {
      long base = (((long)kc * 32 + b) * 12 + lr) * 768 + c0 + mi * 16 + kg * 4;
      *(float4*)&Yp[base] = make_float4(acc[mi][0], acc[mi][1], acc[mi][2], acc[mi][3]);
    }
  }
}

// ---------------- 6. ctx_gemm: ctx[bn][o] = sum_c (sum5 Yp)[bn][c] W[o][c] + cb -
__global__ __launch_bounds__(64) void ctx_gemm(const float* __restrict__ Yp,
                                               const float* __restrict__ W,
                                               float* __restrict__ C,
                                               const float* __restrict__ bias) {
  const long QS = (long)32 * 12 * 768;   // per-kc partial stride
  int n0 = blockIdx.x * 64, m0 = blockIdx.y * 64;
  int lr = threadIdx.x & 15, kg = threadIdx.x >> 4;
  f32x4 acc[4][4] = {};
  for (int k0 = 0; k0 < 768; k0 += 32) {
    frag8 af[4], bv[4];
#pragma unroll
    for (int mi = 0; mi < 4; ++mi) {
      const float* ap = Yp + (long)(m0 + mi * 16 + lr) * 768 + k0 + kg * 8;
      float4 lo = *(const float4*)ap, hi = *(const float4*)(ap + 4);
#pragma unroll
      for (int q = 1; q < 5; ++q) {
        float4 l2 = *(const float4*)(ap + q * QS), h2 = *(const float4*)(ap + q * QS + 4);
        lo.x += l2.x; lo.y += l2.y; lo.z += l2.z; lo.w += l2.w;
        hi.x += h2.x; hi.y += h2.y; hi.z += h2.z; hi.w += h2.w;
      }
      af[mi] = cvt8(lo, hi);
    }
#pragma unroll
    for (int ni = 0; ni < 4; ++ni) {
      const float* bp = W + (long)(n0 + ni * 16 + lr) * 768 + k0 + kg * 8;
      bv[ni] = cvt8(*(const float4*)bp, *(const float4*)(bp + 4));
    }
#pragma unroll
    for (int mi = 0; mi < 4; ++mi)
#pragma unroll
      for (int ni = 0; ni < 4; ++ni)
        acc[mi][ni] = __builtin_amdgcn_mfma_f32_16x16x32_bf16(af[mi], bv[ni],
                                                              acc[mi][ni], 0, 0, 0);
  }
#pragma unroll
  for (int mi = 0; mi < 4; ++mi)
#pragma unroll
    for (int ni = 0; ni < 4; ++ni)
#pragma unroll
      for (int j = 0; j < 4; ++j) {
        int row = m0 + mi * 16 + kg * 4 + j;
        int col = n0 + ni * 16 + lr;
        C[(long)row * 256 + col] = acc[mi][ni][j] + bias[col];
      }
}

// ---------------- 7. LayerNorm over 256: LN(a + bb) ----------------------------
__global__ __launch_bounds__(256) void ln_k(const float* __restrict__ a,
                                            const float* __restrict__ bb,
                                            const float* __restrict__ g,
                                            const float* __restrict__ be,
                                            float* __restrict__ of) {
  int r = blockIdx.x, c = threadIdx.x;
  long idx = (long)r * 256 + c;
  float v = a[idx] + bb[idx];
  float s = wred_sum(v);
  float s2 = wred_sum(v * v);
  __shared__ float r1[4], r2[4];
  int w = c >> 6, lane = c & 63;
  if (lane == 0) { r1[w] = s; r2[w] = s2; }
  __syncthreads();
  float st = r1[0] + r1[1] + r1[2] + r1[3];
  float s2t = r2[0] + r2[1] + r2[2] + r2[3];
  float mean = st * (1.f / 256.f);
  float var = s2t * (1.f / 256.f) - mean * mean;
  float rs = rsqrtf(var + 1e-5f);
  of[idx] = (v - mean) * rs * g[c] + be[c];
}

// ---------------- launcher -----------------------------------------------------
extern "C" void kernel_launch(void* const* d_in, const int* in_sizes, int n_in,
                              void* d_out, int out_size, void* d_ws, size_t ws_size,
                              hipStream_t stream) {
  const float* roi   = (const float*)d_in[0];
  const float* imgf  = (const float*)d_in[1];
  const float* convw = (const float*)d_in[2];
  const float* convb = (const float*)d_in[3];
  const float* embw  = (const float*)d_in[4];
  const float* embb  = (const float*)d_in[5];
  const float* ln1g  = (const float*)d_in[6];
  const float* ln1b  = (const float*)d_in[7];
  const float* w1    = (const float*)d_in[8];
  const float* b1    = (const float*)d_in[9];
  const float* w2    = (const float*)d_in[10];
  const float* b2    = (const float*)d_in[11];
  const float* ln2g  = (const float*)d_in[12];
  const float* ln2b  = (const float*)d_in[13];
  float* out = (float*)d_out;

  char* p = (char*)d_ws;
  size_t off = 0;
  auto take = [&](size_t sz) -> char* {
    char* r = p + off;
    off += (sz + 255) & ~(size_t)255;
    return r;
  };
  float* emb  = (float*)take((size_t)384 * 256 * 4);
  bf16*  Wt   = (bf16*)take((size_t)768 * 256 * 2);
  float* embW = (float*)take((size_t)384 * 768 * 4);
  float* lgt  = (float*)take((size_t)2 * 384 * 1204 * 4);
  bf16*  am   = (bf16*)take((size_t)32 * 16 * 1280 * 2);
  float* Yp   = (float*)take((size_t)5 * 32 * 12 * 768 * 4);
  float* ctxf = (float*)take((size_t)384 * 256 * 4);
  float* x    = (float*)take((size_t)384 * 256 * 4);
  bf16*  h1   = (bf16*)take((size_t)384 * 256 * 2);
  float* h    = (float*)take((size_t)384 * 256 * 4);

  // 1. emb = roi @ embw^T + embb   [384][256] fp32
  gemm_sm2<true, true, false, false, true><<<dim3(4, 6), 64, 0, stream>>>(
      roi, embw, emb, 1024, 256, embb);
  // 2. Wt = conv_w^T (bf16)       [768][256]
  wt_k<<<dim3(24, 8), 256, 0, stream>>>(convw, Wt);
  // 3. embW = emb @ conv_w        [384][768] fp32  (B rows = Wt rows, K=256)
  gemm_sm2<true, false, false, false, false><<<dim3(12, 6), 64, 0, stream>>>(
      emb, Wt, embW, 256, 768, nullptr);
  // 4. logits partials over c-halves (softmax shift-invariance kills bias term)
  logits2<<<dim3(5, 2, 32), 256, 0, stream>>>(imgf, embW, lgt);
  // 5. softmax -> am bf16 (rows 12..15 zero)
  softmax2<<<dim3(32, 16), 256, 0, stream>>>(lgt, am);
  // 6. Y partials: Yp[kc][b][n][c] = sum_p X*A  (MFMA, K=p, no transpose)
  ctx_a<<<dim3(12, 5, 32), 64, 0, stream>>>(imgf, am, Yp);
  // 7. ctx = W @ Ysum + conv_b    [384][256] fp32
  ctx_gemm<<<dim3(4, 6), 64, 0, stream>>>(Yp, convw, ctxf, convb);
  // 8. LN1 -> x
  ln_k<<<384, 256, 0, stream>>>(ctxf, emb, ln1g, ln1b, x);
  // 9. FFN1: relu(x @ w1^T + b1) -> h1 bf16
  gemm_sm2<true, true, true, true, true><<<dim3(4, 6), 64, 0, stream>>>(
      x, w1, h1, 256, 256, b1);
  // 10. FFN2: h1 @ w2^T + b2 -> h fp32
  gemm_sm2<false, true, false, false, true><<<dim3(4, 6), 64, 0, stream>>>(
      h1, w2, h, 256, 256, b2);
  // 11. LN2 -> out
  ln_k<<<384, 256, 0, stream>>>(h, x, ln2g, ln2b, out);
}

// Round 10
// 150.053 us; speedup vs baseline: 1.7227x; 1.7227x over previous
//
#include <hip/hip_runtime.h>
#include <hip/hip_bf16.h>
#include <stdint.h>

typedef __hip_bfloat16 bf16;
typedef __attribute__((ext_vector_type(8))) __bf16 frag8;
typedef __attribute__((ext_vector_type(4))) float f32x4;

// ---------------- helpers ----------------
__device__ inline float wred_sum(float v) {
#pragma unroll
  for (int o = 32; o; o >>= 1) v += __shfl_down(v, o);
  return v;
}
__device__ inline float wred_max(float v) {
#pragma unroll
  for (int o = 32; o; o >>= 1) v = fmaxf(v, __shfl_down(v, o));
  return v;
}
__device__ inline unsigned short bits_of(bf16 h) { return *(unsigned short*)&h; }
__device__ inline frag8 cvt8(float4 lo, float4 hi) {
  union { frag8 f; unsigned short u[8]; } r;
  r.u[0] = bits_of(__float2bfloat16(lo.x));
  r.u[1] = bits_of(__float2bfloat16(lo.y));
  r.u[2] = bits_of(__float2bfloat16(lo.z));
  r.u[3] = bits_of(__float2bfloat16(lo.w));
  r.u[4] = bits_of(__float2bfloat16(hi.x));
  r.u[5] = bits_of(__float2bfloat16(hi.y));
  r.u[6] = bits_of(__float2bfloat16(hi.z));
  r.u[7] = bits_of(__float2bfloat16(hi.w));
  return r.f;
}

// ---------------- 1. W[256][768] f32 -> Wt[768][256] bf16 ----------------------
__global__ __launch_bounds__(256) void wt_k(const float* __restrict__ W,
                                            bf16* __restrict__ Wt) {
  __shared__ float t[32][33];
  int c0 = blockIdx.x * 32, o0 = blockIdx.y * 32;
  int tx = threadIdx.x & 31, ty = threadIdx.x >> 5;
#pragma unroll
  for (int i = 0; i < 4; ++i)
    t[ty + i * 8][tx] = W[(long)(o0 + ty + i * 8) * 768 + c0 + tx];
  __syncthreads();
#pragma unroll
  for (int i = 0; i < 4; ++i)
    Wt[(long)(c0 + ty + i * 8) * 256 + o0 + tx] = __float2bfloat16(t[tx][ty + i * 8]);
}

// ---------------- 2. small barrier-free GEMM, one wave per 64x(16*NT) tile -----
// C[m][n] = sum_k A[m][k]*B[n][k] (+ bias[n]); A,B row-major with row stride K.
template <int NT, bool AF32, bool BF32, bool RELU, bool OUT_BF16, bool BIAS>
__global__ __launch_bounds__(64) void gemm_sm2(const void* __restrict__ Av,
                                               const void* __restrict__ Bv,
                                               void* __restrict__ C, int K, int ldc,
                                               const float* __restrict__ bias) {
  int n0 = blockIdx.x * (16 * NT), m0 = blockIdx.y * 64;
  int lr = threadIdx.x & 15, kg = threadIdx.x >> 4;
  f32x4 acc[4][NT] = {};
#pragma unroll 2
  for (int k0 = 0; k0 < K; k0 += 32) {
    frag8 af[4], bv[NT];
#pragma unroll
    for (int mi = 0; mi < 4; ++mi) {
      long row = m0 + mi * 16 + lr;
      if constexpr (AF32) {
        const float* ap = (const float*)Av + row * K + k0 + kg * 8;
        af[mi] = cvt8(*(const float4*)ap, *(const float4*)(ap + 4));
      } else {
        af[mi] = *(const frag8*)((const bf16*)Av + row * K + k0 + kg * 8);
      }
    }
#pragma unroll
    for (int ni = 0; ni < NT; ++ni) {
      long row = n0 + ni * 16 + lr;
      if constexpr (BF32) {
        const float* bp = (const float*)Bv + row * K + k0 + kg * 8;
        bv[ni] = cvt8(*(const float4*)bp, *(const float4*)(bp + 4));
      } else {
        bv[ni] = *(const frag8*)((const bf16*)Bv + row * K + k0 + kg * 8);
      }
    }
#pragma unroll
    for (int mi = 0; mi < 4; ++mi)
#pragma unroll
      for (int ni = 0; ni < NT; ++ni)
        acc[mi][ni] = __builtin_amdgcn_mfma_f32_16x16x32_bf16(af[mi], bv[ni],
                                                              acc[mi][ni], 0, 0, 0);
  }
#pragma unroll
  for (int mi = 0; mi < 4; ++mi)
#pragma unroll
    for (int ni = 0; ni < NT; ++ni)
#pragma unroll
      for (int j = 0; j < 4; ++j) {
        int row = m0 + mi * 16 + kg * 4 + j;
        int col = n0 + ni * 16 + lr;
        float v = acc[mi][ni][j];
        if (BIAS) v += bias[col];
        if (RELU) v = fmaxf(v, 0.f);
        long idx = (long)row * ldc + col;
        if constexpr (OUT_BF16) ((bf16*)C)[idx] = __float2bfloat16(v);
        else ((float*)C)[idx] = v;
      }
}

// ---------------- 3. logits2: lgt[cs][b*12+n][p] = sum_{c in half} embW*X ------
// Bias term emb.conv_b is constant over p -> drops out of softmax (shift-inv).
__global__ __launch_bounds__(256) void logits2(const float* __restrict__ X,
                                               const float* __restrict__ embW,
                                               float* __restrict__ lgt) {
  int px = blockIdx.x, cs = blockIdx.y, b = blockIdx.z;
  __shared__ float e[12 * 384];   // 18 KB
  for (int i = threadIdx.x; i < 12 * 384; i += 256)
    e[i] = embW[((long)b * 12 + i / 384) * 768 + cs * 384 + (i % 384)];
  __syncthreads();
  int p = px * 256 + threadIdx.x;
  if (p >= 1204) return;
  const float* xb = X + ((long)b * 768 + cs * 384) * 1204 + p;
  float acc[12] = {};
#pragma unroll 8
  for (int c = 0; c < 384; ++c) {
    float xv = xb[(long)c * 1204];
#pragma unroll
    for (int n = 0; n < 12; ++n) acc[n] += e[n * 384 + c] * xv;
  }
#pragma unroll
  for (int n = 0; n < 12; ++n)
    lgt[((long)cs * 384 + b * 12 + n) * 1204 + p] = acc[n];
}

// ---------------- 4. softmax (2 partials) -> am [32][16][1280] bf16 zero-pad ---
__global__ __launch_bounds__(256) void softmax2(const float* __restrict__ lgt,
                                                bf16* __restrict__ am) {
  int b = blockIdx.x, n = blockIdx.y, tid = threadIdx.x;
  bf16* row = am + ((long)b * 16 + n) * 1280;
  if (n >= 12) {
    for (int i = tid; i < 1280; i += 256) row[i] = __float2bfloat16(0.f);
    return;
  }
  const float* l0 = lgt + ((long)b * 12 + n) * 1204;
  const float* l1 = l0 + (long)384 * 1204;
  float vals[5];
  float m = -3.0e38f;
#pragma unroll
  for (int i = 0; i < 5; ++i) {
    int pp = tid + i * 256;
    vals[i] = (pp < 1204) ? (l0[pp] + l1[pp]) : -3.0e38f;
    m = fmaxf(m, vals[i]);
  }
  m = wred_max(m);
  __shared__ float rd[4];
  int w = tid >> 6, lane = tid & 63;
  if (lane == 0) rd[w] = m;
  __syncthreads();
  m = fmaxf(fmaxf(rd[0], rd[1]), fmaxf(rd[2], rd[3]));
  float s = 0.f;
#pragma unroll
  for (int i = 0; i < 5; ++i) {
    int pp = tid + i * 256;
    vals[i] = (pp < 1204) ? __expf(vals[i] - m) : 0.f;
    s += vals[i];
  }
  s = wred_sum(s);
  __syncthreads();
  if (lane == 0) rd[w] = s;
  __syncthreads();
  s = rd[0] + rd[1] + rd[2] + rd[3];
  float inv = 1.f / s;
#pragma unroll
  for (int i = 0; i < 5; ++i) {
    int pp = tid + i * 256;
    row[pp] = __float2bfloat16((pp < 1204) ? vals[i] * inv : 0.f);
  }
}

// ---------------- 5. ctx_a: Yp[kc][b][n][c] = sum_{p in chunk} X[b][c][p]A[n][p]
// TN MFMA with K = p: BOTH operands p-contiguous, no transpose. 1 wave/block.
__global__ __launch_bounds__(64) void ctx_a(const float* __restrict__ X,
                                            const bf16* __restrict__ am,
                                            float* __restrict__ Yp) {
  int ct = blockIdx.x, kc = blockIdx.y, b = blockIdx.z;
  int c0 = ct * 64;
  int kst = kc * 256, kend = min(kst + 256, 1204);
  int lr = threadIdx.x & 15, kg = threadIdx.x >> 4;
  f32x4 acc[4] = {};
  for (int k0 = kst; k0 < kend; k0 += 32) {
    frag8 bv = *(const frag8*)(am + ((long)b * 16 + lr) * 1280 + k0 + kg * 8);
    bool full = (k0 + 32 <= 1204);
#pragma unroll
    for (int mi = 0; mi < 4; ++mi) {
      const float* ap = X + ((long)b * 768 + c0 + mi * 16 + lr) * 1204 + k0 + kg * 8;
      frag8 av;
      if (full) {
        av = cvt8(*(const float4*)ap, *(const float4*)(ap + 4));
      } else {
        float t[8];
#pragma unroll
        for (int j = 0; j < 8; ++j)
          t[j] = (k0 + kg * 8 + j < 1204) ? ap[j] : 0.f;   // A=0 there anyway
        av = cvt8(make_float4(t[0], t[1], t[2], t[3]),
                  make_float4(t[4], t[5], t[6], t[7]));
      }
      acc[mi] = __builtin_amdgcn_mfma_f32_16x16x32_bf16(av, bv, acc[mi], 0, 0, 0);
    }
  }
  if (lr < 12) {
#pragma unroll
    for (int mi = 0; mi < 4; ++mi) {
      long base = (((long)kc * 32 + b) * 12 + lr) * 768 + c0 + mi * 16 + kg * 4;
      *(float4*)&Yp[base] = make_float4(acc[mi][0], acc[mi][1], acc[mi][2], acc[mi][3]);
    }
  }
}

// ---------------- 6. red_y: Ysum[i] = sum_{q<5} Yp[q][i], bf16 out -------------
__global__ __launch_bounds__(256) void red_y(const float* __restrict__ Yp,
                                             bf16* __restrict__ Ysum) {
  const long QS = (long)32 * 12 * 768;   // 294912
  long i = ((long)blockIdx.x * 256 + threadIdx.x) * 4;
  if (i >= QS) return;
  float4 v = *(const float4*)(Yp + i);
#pragma unroll
  for (int q = 1; q < 5; ++q) {
    float4 u = *(const float4*)(Yp + q * QS + i);
    v.x += u.x; v.y += u.y; v.z += u.z; v.w += u.w;
  }
  union { ushort4 s; bf16 h[4]; } o;
  o.h[0] = __float2bfloat16(v.x);
  o.h[1] = __float2bfloat16(v.y);
  o.h[2] = __float2bfloat16(v.z);
  o.h[3] = __float2bfloat16(v.w);
  *(ushort4*)(Ysum + i) = o.s;
}

// ---------------- 7. LayerNorm over 256: LN(a + bb) ----------------------------
__global__ __launch_bounds__(256) void ln_k(const float* __restrict__ a,
                                            const float* __restrict__ bb,
                                            const float* __restrict__ g,
                                            const float* __restrict__ be,
                                            float* __restrict__ of) {
  int r = blockIdx.x, c = threadIdx.x;
  long idx = (long)r * 256 + c;
  float v = a[idx] + bb[idx];
  float s = wred_sum(v);
  float s2 = wred_sum(v * v);
  __shared__ float r1[4], r2[4];
  int w = c >> 6, lane = c & 63;
  if (lane == 0) { r1[w] = s; r2[w] = s2; }
  __syncthreads();
  float st = r1[0] + r1[1] + r1[2] + r1[3];
  float s2t = r2[0] + r2[1] + r2[2] + r2[3];
  float mean = st * (1.f / 256.f);
  float var = s2t * (1.f / 256.f) - mean * mean;
  float rs = rsqrtf(var + 1e-5f);
  of[idx] = (v - mean) * rs * g[c] + be[c];
}

// ---------------- launcher -----------------------------------------------------
extern "C" void kernel_launch(void* const* d_in, const int* in_sizes, int n_in,
                              void* d_out, int out_size, void* d_ws, size_t ws_size,
                              hipStream_t stream) {
  const float* roi   = (const float*)d_in[0];
  const float* imgf  = (const float*)d_in[1];
  const float* convw = (const float*)d_in[2];
  const float* convb = (const float*)d_in[3];
  const float* embw  = (const float*)d_in[4];
  const float* embb  = (const float*)d_in[5];
  const float* ln1g  = (const float*)d_in[6];
  const float* ln1b  = (const float*)d_in[7];
  const float* w1    = (const float*)d_in[8];
  const float* b1    = (const float*)d_in[9];
  const float* w2    = (const float*)d_in[10];
  const float* b2    = (const float*)d_in[11];
  const float* ln2g  = (const float*)d_in[12];
  const float* ln2b  = (const float*)d_in[13];
  float* out = (float*)d_out;

  char* p = (char*)d_ws;
  size_t off = 0;
  auto take = [&](size_t sz) -> char* {
    char* r = p + off;
    off += (sz + 255) & ~(size_t)255;
    return r;
  };
  float* emb  = (float*)take((size_t)384 * 256 * 4);
  bf16*  Wt   = (bf16*)take((size_t)768 * 256 * 2);
  float* embW = (float*)take((size_t)384 * 768 * 4);
  float* lgt  = (float*)take((size_t)2 * 384 * 1204 * 4);
  bf16*  am   = (bf16*)take((size_t)32 * 16 * 1280 * 2);
  float* Yp   = (float*)take((size_t)5 * 32 * 12 * 768 * 4);
  bf16*  Ysum = (bf16*)take((size_t)384 * 768 * 2);
  float* ctxf = (float*)take((size_t)384 * 256 * 4);
  float* x    = (float*)take((size_t)384 * 256 * 4);
  bf16*  h1   = (bf16*)take((size_t)384 * 256 * 2);
  float* h    = (float*)take((size_t)384 * 256 * 4);

  // 1. emb = roi @ embw^T + embb   [384][256] fp32   (96 blocks)
  gemm_sm2<1, true, true, false, false, true><<<dim3(16, 6), 64, 0, stream>>>(
      roi, embw, emb, 1024, 256, embb);
  // 2. Wt = conv_w^T (bf16)       [768][256]
  wt_k<<<dim3(24, 8), 256, 0, stream>>>(convw, Wt);
  // 3. embW = emb @ conv_w        [384][768] fp32   (288 blocks)
  gemm_sm2<1, true, false, false, false, false><<<dim3(48, 6), 64, 0, stream>>>(
      emb, Wt, embW, 256, 768, nullptr);
  // 4. logits partials over c-halves (softmax shift-invariance kills bias term)
  logits2<<<dim3(5, 2, 32), 256, 0, stream>>>(imgf, embW, lgt);
  // 5. softmax -> am bf16 (rows 12..15 zero)
  softmax2<<<dim3(32, 16), 256, 0, stream>>>(lgt, am);
  // 6. Y partials: Yp[kc][b][n][c] = sum_p X*A  (MFMA, K=p, no transpose)
  ctx_a<<<dim3(12, 5, 32), 64, 0, stream>>>(imgf, am, Yp);
  // 7. Ysum = sum partials -> bf16  (288 blocks, streaming)
  red_y<<<288, 256, 0, stream>>>(Yp, Ysum);
  // 8. ctx = Ysum @ conv_w^T + conv_b  [384][256] fp32  (96 blocks)
  gemm_sm2<1, false, true, false, false, true><<<dim3(16, 6), 64, 0, stream>>>(
      Ysum, convw, ctxf, 768, 256, convb);
  // 9. LN1 -> x
  ln_k<<<384, 256, 0, stream>>>(ctxf, emb, ln1g, ln1b, x);
  // 10. FFN1: relu(x @ w1^T + b1) -> h1 bf16  (96 blocks)
  gemm_sm2<1, true, true, true, true, true><<<dim3(16, 6), 64, 0, stream>>>(
      x, w1, h1, 256, 256, b1);
  // 11. FFN2: h1 @ w2^T + b2 -> h fp32  (96 blocks)
  gemm_sm2<1, false, true, false, false, true><<<dim3(16, 6), 64, 0, stream>>>(
      h1, w2, h, 256, 256, b2);
  // 12. LN2 -> out
  ln_k<<<384, 256, 0, stream>>>(h, x, ln2g, ln2b, out);
}

// Round 11
// 137.802 us; speedup vs baseline: 1.8759x; 1.0889x over previous
//
#include <hip/hip_runtime.h>
#include <hip/hip_bf16.h>
#include <stdint.h>

typedef __hip_bfloat16 bf16;
typedef __attribute__((ext_vector_type(8))) __bf16 frag8;
typedef __attribute__((ext_vector_type(4))) float f32x4;

// ---------------- helpers ----------------
__device__ inline float wred_sum(float v) {
#pragma unroll
  for (int o = 32; o; o >>= 1) v += __shfl_down(v, o);
  return v;
}
__device__ inline float wred_max(float v) {
#pragma unroll
  for (int o = 32; o; o >>= 1) v = fmaxf(v, __shfl_down(v, o));
  return v;
}
__device__ inline unsigned short bits_of(bf16 h) { return *(unsigned short*)&h; }
__device__ inline frag8 cvt8(float4 lo, float4 hi) {
  union { frag8 f; unsigned short u[8]; } r;
  r.u[0] = bits_of(__float2bfloat16(lo.x));
  r.u[1] = bits_of(__float2bfloat16(lo.y));
  r.u[2] = bits_of(__float2bfloat16(lo.z));
  r.u[3] = bits_of(__float2bfloat16(lo.w));
  r.u[4] = bits_of(__float2bfloat16(hi.x));
  r.u[5] = bits_of(__float2bfloat16(hi.y));
  r.u[6] = bits_of(__float2bfloat16(hi.z));
  r.u[7] = bits_of(__float2bfloat16(hi.w));
  return r.f;
}

// ---------------- 1. W[256][768] f32 -> Wt[768][256] bf16 ----------------------
__global__ __launch_bounds__(256) void wt_k(const float* __restrict__ W,
                                            bf16* __restrict__ Wt) {
  __shared__ float t[32][33];
  int c0 = blockIdx.x * 32, o0 = blockIdx.y * 32;
  int tx = threadIdx.x & 31, ty = threadIdx.x >> 5;
#pragma unroll
  for (int i = 0; i < 4; ++i)
    t[ty + i * 8][tx] = W[(long)(o0 + ty + i * 8) * 768 + c0 + tx];
  __syncthreads();
#pragma unroll
  for (int i = 0; i < 4; ++i)
    Wt[(long)(c0 + ty + i * 8) * 256 + o0 + tx] = __float2bfloat16(t[tx][ty + i * 8]);
}

// ---------------- 2. small barrier-free GEMM, one wave per 64x(16*NT) tile -----
template <int NT, bool AF32, bool BF32, bool RELU, bool OUT_BF16, bool BIAS>
__global__ __launch_bounds__(64) void gemm_sm2(const void* __restrict__ Av,
                                               const void* __restrict__ Bv,
                                               void* __restrict__ C, int K, int ldc,
                                               const float* __restrict__ bias) {
  int n0 = blockIdx.x * (16 * NT), m0 = blockIdx.y * 64;
  int lr = threadIdx.x & 15, kg = threadIdx.x >> 4;
  f32x4 acc[4][NT] = {};
#pragma unroll 2
  for (int k0 = 0; k0 < K; k0 += 32) {
    frag8 af[4], bv[NT];
#pragma unroll
    for (int mi = 0; mi < 4; ++mi) {
      long row = m0 + mi * 16 + lr;
      if constexpr (AF32) {
        const float* ap = (const float*)Av + row * K + k0 + kg * 8;
        af[mi] = cvt8(*(const float4*)ap, *(const float4*)(ap + 4));
      } else {
        af[mi] = *(const frag8*)((const bf16*)Av + row * K + k0 + kg * 8);
      }
    }
#pragma unroll
    for (int ni = 0; ni < NT; ++ni) {
      long row = n0 + ni * 16 + lr;
      if constexpr (BF32) {
        const float* bp = (const float*)Bv + row * K + k0 + kg * 8;
        bv[ni] = cvt8(*(const float4*)bp, *(const float4*)(bp + 4));
      } else {
        bv[ni] = *(const frag8*)((const bf16*)Bv + row * K + k0 + kg * 8);
      }
    }
#pragma unroll
    for (int mi = 0; mi < 4; ++mi)
#pragma unroll
      for (int ni = 0; ni < NT; ++ni)
        acc[mi][ni] = __builtin_amdgcn_mfma_f32_16x16x32_bf16(af[mi], bv[ni],
                                                              acc[mi][ni], 0, 0, 0);
  }
#pragma unroll
  for (int mi = 0; mi < 4; ++mi)
#pragma unroll
    for (int ni = 0; ni < NT; ++ni)
#pragma unroll
      for (int j = 0; j < 4; ++j) {
        int row = m0 + mi * 16 + kg * 4 + j;
        int col = n0 + ni * 16 + lr;
        float v = acc[mi][ni][j];
        if (BIAS) v += bias[col];
        if (RELU) v = fmaxf(v, 0.f);
        long idx = (long)row * ldc + col;
        if constexpr (OUT_BF16) ((bf16*)C)[idx] = __float2bfloat16(v);
        else ((float*)C)[idx] = v;
      }
}

// ---------------- 3. logits2: lgt[cs][b*12+n][p..p+3] over 8 c-chunks of 96 ----
// float4 per thread (1204 = 301*4 exactly; rows 16B-aligned: 4816%16==0).
// Bias term (emb.conv_b, const over p) drops out of softmax (shift-invariance).
__global__ __launch_bounds__(256) void logits2(const float* __restrict__ X,
                                               const float* __restrict__ embW,
                                               float* __restrict__ lgt) {
  int px = blockIdx.x, cs = blockIdx.y, b = blockIdx.z;
  __shared__ float e[12 * 96];   // 4.6 KB
  for (int i = threadIdx.x; i < 12 * 96; i += 256)
    e[i] = embW[((long)b * 12 + i / 96) * 768 + cs * 96 + (i % 96)];
  __syncthreads();
  int slot = px * 256 + threadIdx.x;
  if (slot >= 301) return;
  int p = slot * 4;
  const float* xb = X + ((long)b * 768 + cs * 96) * 1204 + p;
  float a0[12], a1[12], a2[12], a3[12];
#pragma unroll
  for (int n = 0; n < 12; ++n) { a0[n] = a1[n] = a2[n] = a3[n] = 0.f; }
#pragma unroll 4
  for (int c = 0; c < 96; ++c) {
    float4 xq = *(const float4*)(xb + (long)c * 1204);
#pragma unroll
    for (int n = 0; n < 12; ++n) {
      float en = e[n * 96 + c];
      a0[n] += en * xq.x; a1[n] += en * xq.y;
      a2[n] += en * xq.z; a3[n] += en * xq.w;
    }
  }
#pragma unroll
  for (int n = 0; n < 12; ++n)
    *(float4*)&lgt[((long)cs * 384 + b * 12 + n) * 1204 + p] =
        make_float4(a0[n], a1[n], a2[n], a3[n]);
}

// ---------------- 4. softmax (8 partials) -> am [32][16][1280] bf16 zero-pad ---
__global__ __launch_bounds__(256) void softmax2(const float* __restrict__ lgt,
                                                bf16* __restrict__ am) {
  const long PS = (long)384 * 1204;
  int b = blockIdx.x, n = blockIdx.y, tid = threadIdx.x;
  bf16* row = am + ((long)b * 16 + n) * 1280;
  if (n >= 12) {
    for (int i = tid; i < 1280; i += 256) row[i] = __float2bfloat16(0.f);
    return;
  }
  const float* l0 = lgt + ((long)b * 12 + n) * 1204;
  float vals[5];
  float m = -3.0e38f;
#pragma unroll
  for (int i = 0; i < 5; ++i) {
    int pp = tid + i * 256;
    if (pp < 1204) {
      float v = 0.f;
#pragma unroll
      for (int q = 0; q < 8; ++q) v += l0[q * PS + pp];
      vals[i] = v;
    } else {
      vals[i] = -3.0e38f;
    }
    m = fmaxf(m, vals[i]);
  }
  m = wred_max(m);
  __shared__ float rd[4];
  int w = tid >> 6, lane = tid & 63;
  if (lane == 0) rd[w] = m;
  __syncthreads();
  m = fmaxf(fmaxf(rd[0], rd[1]), fmaxf(rd[2], rd[3]));
  float s = 0.f;
#pragma unroll
  for (int i = 0; i < 5; ++i) {
    int pp = tid + i * 256;
    vals[i] = (pp < 1204) ? __expf(vals[i] - m) : 0.f;
    s += vals[i];
  }
  s = wred_sum(s);
  __syncthreads();
  if (lane == 0) rd[w] = s;
  __syncthreads();
  s = rd[0] + rd[1] + rd[2] + rd[3];
  float inv = 1.f / s;
#pragma unroll
  for (int i = 0; i < 5; ++i) {
    int pp = tid + i * 256;
    row[pp] = __float2bfloat16((pp < 1204) ? vals[i] * inv : 0.f);
  }
}

// ---------------- 5. ctx_a: Yp[kc][b][n][c] = sum_{p in chunk} X[b][c][p]A[n][p]
__global__ __launch_bounds__(64) void ctx_a(const float* __restrict__ X,
                                            const bf16* __restrict__ am,
                                            float* __restrict__ Yp) {
  int ct = blockIdx.x, kc = blockIdx.y, b = blockIdx.z;
  int c0 = ct * 64;
  int kst = kc * 256, kend = min(kst + 256, 1204);
  int lr = threadIdx.x & 15, kg = threadIdx.x >> 4;
  f32x4 acc[4] = {};
  for (int k0 = kst; k0 < kend; k0 += 32) {
    frag8 bv = *(const frag8*)(am + ((long)b * 16 + lr) * 1280 + k0 + kg * 8);
    bool full = (k0 + 32 <= 1204);
#pragma unroll
    for (int mi = 0; mi < 4; ++mi) {
      const float* ap = X + ((long)b * 768 + c0 + mi * 16 + lr) * 1204 + k0 + kg * 8;
      frag8 av;
      if (full) {
        av = cvt8(*(const float4*)ap, *(const float4*)(ap + 4));
      } else {
        float t[8];
#pragma unroll
        for (int j = 0; j < 8; ++j)
          t[j] = (k0 + kg * 8 + j < 1204) ? ap[j] : 0.f;   // A=0 there anyway
        av = cvt8(make_float4(t[0], t[1], t[2], t[3]),
                  make_float4(t[4], t[5], t[6], t[7]));
      }
      acc[mi] = __builtin_amdgcn_mfma_f32_16x16x32_bf16(av, bv, acc[mi], 0, 0, 0);
    }
  }
  if (lr < 12) {
#pragma unroll
    for (int mi = 0; mi < 4; ++mi) {
      long base = (((long)kc * 32 + b) * 12 + lr) * 768 + c0 + mi * 16 + kg * 4;
      *(float4*)&Yp[base] = make_float4(acc[mi][0], acc[mi][1], acc[mi][2], acc[mi][3]);
    }
  }
}

// ---------------- 6. red_y: Ysum[i] = sum_{q<5} Yp[q][i], bf16 out -------------
__global__ __launch_bounds__(256) void red_y(const float* __restrict__ Yp,
                                             bf16* __restrict__ Ysum) {
  const long QS = (long)32 * 12 * 768;   // 294912
  long i = ((long)blockIdx.x * 256 + threadIdx.x) * 4;
  if (i >= QS) return;
  float4 v = *(const float4*)(Yp + i);
#pragma unroll
  for (int q = 1; q < 5; ++q) {
    float4 u = *(const float4*)(Yp + q * QS + i);
    v.x += u.x; v.y += u.y; v.z += u.z; v.w += u.w;
  }
  union { ushort4 s; bf16 h[4]; } o;
  o.h[0] = __float2bfloat16(v.x);
  o.h[1] = __float2bfloat16(v.y);
  o.h[2] = __float2bfloat16(v.z);
  o.h[3] = __float2bfloat16(v.w);
  *(ushort4*)(Ysum + i) = o.s;
}

// ---------------- 7. LayerNorm over 256: LN(a + bb) ----------------------------
__global__ __launch_bounds__(256) void ln_k(const float* __restrict__ a,
                                            const float* __restrict__ bb,
                                            const float* __restrict__ g,
                                            const float* __restrict__ be,
                                            float* __restrict__ of) {
  int r = blockIdx.x, c = threadIdx.x;
  long idx = (long)r * 256 + c;
  float v = a[idx] + bb[idx];
  float s = wred_sum(v);
  float s2 = wred_sum(v * v);
  __shared__ float r1[4], r2[4];
  int w = c >> 6, lane = c & 63;
  if (lane == 0) { r1[w] = s; r2[w] = s2; }
  __syncthreads();
  float st = r1[0] + r1[1] + r1[2] + r1[3];
  float s2t = r2[0] + r2[1] + r2[2] + r2[3];
  float mean = st * (1.f / 256.f);
  float var = s2t * (1.f / 256.f) - mean * mean;
  float rs = rsqrtf(var + 1e-5f);
  of[idx] = (v - mean) * rs * g[c] + be[c];
}

// ---------------- launcher -----------------------------------------------------
extern "C" void kernel_launch(void* const* d_in, const int* in_sizes, int n_in,
                              void* d_out, int out_size, void* d_ws, size_t ws_size,
                              hipStream_t stream) {
  const float* roi   = (const float*)d_in[0];
  const float* imgf  = (const float*)d_in[1];
  const float* convw = (const float*)d_in[2];
  const float* convb = (const float*)d_in[3];
  const float* embw  = (const float*)d_in[4];
  const float* embb  = (const float*)d_in[5];
  const float* ln1g  = (const float*)d_in[6];
  const float* ln1b  = (const float*)d_in[7];
  const float* w1    = (const float*)d_in[8];
  const float* b1    = (const float*)d_in[9];
  const float* w2    = (const float*)d_in[10];
  const float* b2    = (const float*)d_in[11];
  const float* ln2g  = (const float*)d_in[12];
  const float* ln2b  = (const float*)d_in[13];
  float* out = (float*)d_out;

  char* p = (char*)d_ws;
  size_t off = 0;
  auto take = [&](size_t sz) -> char* {
    char* r = p + off;
    off += (sz + 255) & ~(size_t)255;
    return r;
  };
  float* emb  = (float*)take((size_t)384 * 256 * 4);
  bf16*  Wt   = (bf16*)take((size_t)768 * 256 * 2);
  float* embW = (float*)take((size_t)384 * 768 * 4);
  float* lgt  = (float*)take((size_t)8 * 384 * 1204 * 4);
  bf16*  am   = (bf16*)take((size_t)32 * 16 * 1280 * 2);
  float* Yp   = (float*)take((size_t)5 * 32 * 12 * 768 * 4);
  bf16*  Ysum = (bf16*)take((size_t)384 * 768 * 2);
  float* ctxf = (float*)take((size_t)384 * 256 * 4);
  float* x    = (float*)take((size_t)384 * 256 * 4);
  bf16*  h1   = (bf16*)take((size_t)384 * 256 * 2);
  float* h    = (float*)take((size_t)384 * 256 * 4);

  // 1. emb = roi @ embw^T + embb   [384][256] fp32   (96 blocks)
  gemm_sm2<1, true, true, false, false, true><<<dim3(16, 6), 64, 0, stream>>>(
      roi, embw, emb, 1024, 256, embb);
  // 2. Wt = conv_w^T (bf16)       [768][256]
  wt_k<<<dim3(24, 8), 256, 0, stream>>>(convw, Wt);
  // 3. embW = emb @ conv_w        [384][768] fp32   (288 blocks)
  gemm_sm2<1, true, false, false, false, false><<<dim3(48, 6), 64, 0, stream>>>(
      emb, Wt, embW, 256, 768, nullptr);
  // 4. logits partials: 8 c-chunks, float4/thread  (512 blocks)
  logits2<<<dim3(2, 8, 32), 256, 0, stream>>>(imgf, embW, lgt);
  // 5. softmax (sums 8 partials) -> am bf16 (rows 12..15 zero)
  softmax2<<<dim3(32, 16), 256, 0, stream>>>(lgt, am);
  // 6. Y partials: Yp[kc][b][n][c] = sum_p X*A  (MFMA, K=p, no transpose)
  ctx_a<<<dim3(12, 5, 32), 64, 0, stream>>>(imgf, am, Yp);
  // 7. Ysum = sum partials -> bf16  (288 blocks, streaming)
  red_y<<<288, 256, 0, stream>>>(Yp, Ysum);
  // 8. ctx = Ysum @ conv_w^T + conv_b  [384][256] fp32  (96 blocks)
  gemm_sm2<1, false, true, false, false, true><<<dim3(16, 6), 64, 0, stream>>>(
      Ysum, convw, ctxf, 768, 256, convb);
  // 9. LN1 -> x
  ln_k<<<384, 256, 0, stream>>>(ctxf, emb, ln1g, ln1b, x);
  // 10. FFN1: relu(x @ w1^T + b1) -> h1 bf16  (96 blocks)
  gemm_sm2<1, true, true, true, true, true><<<dim3(16, 6), 64, 0, stream>>>(
      x, w1, h1, 256, 256, b1);
  // 11. FFN2: h1 @ w2^T + b2 -> h fp32  (96 blocks)
  gemm_sm2<1, false, true, false, false, true><<<dim3(16, 6), 64, 0, stream>>>(
      h1, w2, h, 256, 256, b2);
  // 12. LN2 -> out
  ln_k<<<384, 256, 0, stream>>>(h, x, ln2g, ln2b, out);
}